// Round 9
// baseline (456.683 us; speedup 1.0000x reference)
//
#include <hip/hip_runtime.h>
#include <hip/hip_bf16.h>

#define MROWS 16384   // B*L
#define DDIM  512
#define HDIM  1024
#define CDIM  8192
#define LN_EPS 1e-5f
#define CAND_MAX 64
#define SCORE_DELTA 3.0f
#define RESCORE_WIN 3.0f

typedef __attribute__((ext_vector_type(8))) short bf16x8;
typedef __attribute__((ext_vector_type(4))) float f32x4;

__device__ __forceinline__ unsigned int f2key(float f) {
  unsigned int b = __float_as_uint(f);
  return (b & 0x80000000u) ? ~b : (b | 0x80000000u);
}
__device__ __forceinline__ float key2f(unsigned int k) {
  unsigned int b = (k & 0x80000000u) ? (k ^ 0x80000000u) : ~k;
  return __uint_as_float(b);
}

// -------- LayerNorm -> bf16 (one wave per row, 4 rows/block) + cnt/rmin init --
__global__ __launch_bounds__(256) void k_ln(const float* __restrict__ x,
                                            const float* __restrict__ lnw,
                                            const float* __restrict__ lnb,
                                            __hip_bfloat16* __restrict__ xb,
                                            unsigned int* __restrict__ cnt,
                                            unsigned int* __restrict__ rmin) {
  const int row = blockIdx.x * 4 + (threadIdx.x >> 6);
  const int t = threadIdx.x & 63;
  if (threadIdx.x < 4) {
    const int g = blockIdx.x * 4 + threadIdx.x;
    cnt[g] = 0u;
    rmin[g] = 0xFFFFFFFFu;
  }
  const float4* xr = (const float4*)(x + (size_t)row * DDIM);
  float4 v0 = xr[2 * t + 0];
  float4 v1 = xr[2 * t + 1];
  float s = v0.x + v0.y + v0.z + v0.w + v1.x + v1.y + v1.z + v1.w;
#pragma unroll
  for (int m = 1; m < 64; m <<= 1) s += __shfl_xor(s, m, 64);
  const float mu = s * (1.0f / DDIM);
  float a0 = v0.x - mu, a1 = v0.y - mu, a2 = v0.z - mu, a3 = v0.w - mu;
  float a4 = v1.x - mu, a5 = v1.y - mu, a6 = v1.z - mu, a7 = v1.w - mu;
  float q = a0*a0 + a1*a1 + a2*a2 + a3*a3 + a4*a4 + a5*a5 + a6*a6 + a7*a7;
#pragma unroll
  for (int m = 1; m < 64; m <<= 1) q += __shfl_xor(q, m, 64);
  const float inv = rsqrtf(q * (1.0f / DDIM) + LN_EPS);
  const float4* wr = (const float4*)lnw;
  const float4* br = (const float4*)lnb;
  float4 w0 = wr[2*t+0], w1 = wr[2*t+1];
  float4 b0 = br[2*t+0], b1 = br[2*t+1];
  float y[8];
  y[0] = a0*inv*w0.x + b0.x;  y[1] = a1*inv*w0.y + b0.y;
  y[2] = a2*inv*w0.z + b0.z;  y[3] = a3*inv*w0.w + b0.w;
  y[4] = a4*inv*w1.x + b1.x;  y[5] = a5*inv*w1.y + b1.y;
  y[6] = a6*inv*w1.z + b1.z;  y[7] = a7*inv*w1.w + b1.w;
  union { unsigned short u[8]; uint4 v4; } o;
#pragma unroll
  for (int i = 0; i < 8; ++i) {
    union { __hip_bfloat16 h; unsigned short us; } cv;
    cv.h = __float2bfloat16(y[i]);
    o.u[i] = cv.us;
  }
  *(uint4*)(xb + (size_t)row * DDIM + 8 * t) = o.v4;
}

// ---------------- c_sq[c] = sum_h cb[h][c]^2 (fp64 accumulate) ----------------
__global__ __launch_bounds__(256) void k_csq(const float* __restrict__ cb,
                                             float* __restrict__ csq_f,
                                             double* __restrict__ csq_d) {
  const int c = blockIdx.x * 256 + threadIdx.x;
  double a = 0.0;
  for (int h = 0; h < HDIM; ++h) {
    float v = cb[(size_t)h * CDIM + c];
    a += (double)v * (double)v;
  }
  csq_f[c] = (float)a;
  csq_d[c] = a;
}

// --- Gt[n][d] = sum_h W[h][d]*cb[h][n] (fp32; 128n x 64d tile, 2 blocks/CU) ---
// Per-element accumulation order is BIT-IDENTICAL to prior rounds: h-chunks of
// 32 ascending, sequential fmaf within chunk into per-chunk sub-accumulator,
// then added to master. Only the thread->element assignment changed.
__global__ __launch_bounds__(256) void k_gproj(const float* __restrict__ W,
                                               const float* __restrict__ cb,
                                               float* __restrict__ Gt,
                                               __hip_bfloat16* __restrict__ Gtb) {
  __shared__ float Ws[32][64];    // [h][d]
  __shared__ float Cs[32][128];   // [h][n]
  const int tx = threadIdx.x;     // 16, d-sub
  const int ty = threadIdx.y;     // 16, n-sub
  const int n0 = blockIdx.x * 128;
  const int d0 = blockIdx.y * 64;
  const int lin = ty * 16 + tx;
  float accm[8][4];               // [n][d]
#pragma unroll
  for (int j = 0; j < 8; ++j)
#pragma unroll
    for (int i = 0; i < 4; ++i) accm[j][i] = 0.0f;

  for (int h0 = 0; h0 < HDIM; h0 += 32) {
    __syncthreads();
#pragma unroll
    for (int i = 0; i < 2; ++i) {   // Ws: 512 float4
      int f = lin + 256 * i;
      int hh = f >> 4, e4 = f & 15;
      ((float4*)&Ws[hh][0])[e4] = ((const float4*)(W + (size_t)(h0 + hh) * DDIM + d0))[e4];
    }
#pragma unroll
    for (int i = 0; i < 4; ++i) {   // Cs: 1024 float4
      int f = lin + 256 * i;
      int hh = f >> 5, e4 = f & 31;
      ((float4*)&Cs[hh][0])[e4] = ((const float4*)(cb + (size_t)(h0 + hh) * CDIM + n0))[e4];
    }
    __syncthreads();
    float accs[8][4];
#pragma unroll
    for (int j = 0; j < 8; ++j)
#pragma unroll
      for (int i = 0; i < 4; ++i) accs[j][i] = 0.0f;
#pragma unroll
    for (int k = 0; k < 32; ++k) {
      float4 av = ((const float4*)&Ws[k][0])[tx];
      float4 bv0 = ((const float4*)&Cs[k][0])[ty];
      float4 bv1 = ((const float4*)&Cs[k][0])[ty + 16];
      float aa[4] = {av.x, av.y, av.z, av.w};
      float bb[8] = {bv0.x, bv0.y, bv0.z, bv0.w, bv1.x, bv1.y, bv1.z, bv1.w};
#pragma unroll
      for (int j = 0; j < 8; ++j)
#pragma unroll
        for (int i = 0; i < 4; ++i) accs[j][i] = fmaf(bb[j], aa[i], accs[j][i]);
    }
#pragma unroll
    for (int j = 0; j < 8; ++j)
#pragma unroll
      for (int i = 0; i < 4; ++i) accm[j][i] += accs[j][i];
  }
#pragma unroll
  for (int j = 0; j < 8; ++j) {
    const int n = n0 + ty * 4 + (j >> 2) * 64 + (j & 3);
    float4 o = make_float4(accm[j][0], accm[j][1], accm[j][2], accm[j][3]);
    ((float4*)(Gt + (size_t)n * DDIM + d0))[tx] = o;
    union { __hip_bfloat16 h; unsigned short us; } c0, c1, c2, c3;
    c0.h = __float2bfloat16(o.x); c1.h = __float2bfloat16(o.y);
    c2.h = __float2bfloat16(o.z); c3.h = __float2bfloat16(o.w);
    ((ushort4*)(Gtb + (size_t)n * DDIM + d0))[tx] = make_ushort4(c0.us, c1.us, c2.us, c3.us);
  }
}

// ==== 128x256 MFMA scoring, PERSISTENT over 8 n-tiles (pipeline never drains) =
// Engine = R6 verified: 512 thr (8 waves, 2Mx4N), per-wave 64x64 acc[4][4];
// LDS slot 24 KB {A [128][32k] bf16 +0, B [256][32k] +8192}, dbuf 48 KB.
// STAGING RULE: gload_lds dest = base + t*16 exactly (3 x 8 KB calls/iter).
// Quad-swizzle (verified zero-conflict): phys slot p holds global chunk
// p ^ ((row>>1)&3); source slot sce = (t&3)^((t>>3)&3); read swz matches.
// Persistence: block owns m-tile x 8 n-tiles. Global iter G = nt*16+kt,
// slot = kt&1 (16 even -> compile-time). Stage(G+1) inside iter G, ACROSS
// tile boundaries: pipeline drains only at the final iter (1/128 vs 1/16).
// Epilogue per n-tile runs with next tile's stage in flight (latency hidden).
// vmcnt invariant: 3 outstanding at iter top; stage -> 6; wait vmcnt(3).

#define GLL(SRC, DST) __builtin_amdgcn_global_load_lds( \
    (const __attribute__((address_space(1))) unsigned int*)(SRC), \
    (__attribute__((address_space(3))) unsigned int*)(DST), 16, 0, 0)

// Stage K-tile KT2 (0..16; 16 rolls to next n-tile's kt=0) of tile NTT.
#define STAGEG(NTT, KT2) { \
  const int kt_ = (KT2) & 15; \
  const int rb_ = ((KT2) & 1) * 24576; \
  const int co_ = kt_ * 32 + sce * 8; \
  const unsigned short* gBn_ = gB + (size_t)((NTT) + ((KT2) >> 4)) * (256 * 512); \
  GLL(gA + (size_t)sr0 * 512 + co_,          lds + rb_ +         t*16); \
  GLL(gBn_ + (size_t)sr0 * 512 + co_,        lds + rb_ +  8192 + t*16); \
  GLL(gBn_ + (size_t)(sr0 + 128) * 512 + co_, lds + rb_ + 16384 + t*16); }

__global__ __launch_bounds__(512, 4) void k_score(
    const __hip_bfloat16* __restrict__ xb,   // [16384][512]
    const __hip_bfloat16* __restrict__ Gtb,  // [8192][512]
    const float* __restrict__ csq,           // [8192]
    unsigned int* __restrict__ rowminG,      // [16384] key-encoded, init 0xFF
    unsigned int* __restrict__ cnt,          // [16384]
    int* __restrict__ candI,                 // [16384][CAND_MAX]
    float* __restrict__ candS)               // [16384][CAND_MAX]
{
  __shared__ __align__(16) char lds[49152];
  __shared__ unsigned int rowthr[128];

  const int t = threadIdx.x;
  const int wave = t >> 6;
  const int lane = t & 63;
  const int l15 = lane & 15;
  const int l4  = lane >> 4;
  const int wm = wave >> 2;   // 2 waves in M (64 rows each)
  const int wn = wave & 3;    // 4 waves in N (64 cols each)

  // 512 blocks = 128 m-tiles x 4 n-groups; m-fastest + bijective XCD swizzle
  const int bid = blockIdx.x;
  const int sbid = (bid & 7) * 64 + (bid >> 3);
  const int ng    = sbid >> 7;    // 0..3
  const int m_blk = sbid & 127;   // 0..127
  const int rowbase  = m_blk * 128;
  const int colgroup = ng * 2048;

  const unsigned short* gA = (const unsigned short*)xb  + (size_t)rowbase  * 512;
  const unsigned short* gB = (const unsigned short*)Gtb + (size_t)colgroup * 512;

  const int sr0 = t >> 2;                     // 0..127
  const int sce = (t & 3) ^ ((t >> 3) & 3);   // inverse-swizzled source slot

  if (t < 128) rowthr[t] = 0xFFFFFFFFu;

  const int swz = ((l4 ^ ((l15 >> 1) & 3)) << 4);
  const int aoffb = (wm * 64 + l15) * 64 + swz;
  const int boffb = (wn * 64 + l15) * 64 + swz;

  f32x4 acc[4][4];
  bf16x8 a[4], b[4];

  // ---- prologue: stage (nt=0, kt=0) ----
  STAGEG(0, 0);

  for (int nt = 0; nt < 8; ++nt) {
#pragma unroll
    for (int i = 0; i < 4; ++i)
#pragma unroll
      for (int j = 0; j < 4; ++j) acc[i][j] = (f32x4){0.f, 0.f, 0.f, 0.f};

#pragma unroll
    for (int kt = 0; kt < 16; ++kt) {
      if (kt < 15) {
        STAGEG(nt, kt + 1);
        asm volatile("s_waitcnt vmcnt(3)" ::: "memory");
      } else {
        if (nt < 7) {
          STAGEG(nt, 16);   // next tile's kt=0, slot 0
          asm volatile("s_waitcnt vmcnt(3)" ::: "memory");
        } else {
          asm volatile("s_waitcnt vmcnt(0)" ::: "memory");
        }
      }
      __builtin_amdgcn_s_barrier();
      __builtin_amdgcn_sched_barrier(0);
      {
        const char* Sb_ = lds + (kt & 1) * 24576;
#pragma unroll
        for (int ni_ = 0; ni_ < 4; ++ni_)
          b[ni_] = *(const bf16x8*)(Sb_ + 8192 + boffb + ni_ * 1024);
#pragma unroll
        for (int mi_ = 0; mi_ < 4; ++mi_)
          a[mi_] = *(const bf16x8*)(Sb_ + aoffb + mi_ * 1024);
        __builtin_amdgcn_s_setprio(1);
#pragma unroll
        for (int mi_ = 0; mi_ < 4; ++mi_)
#pragma unroll
          for (int ni_ = 0; ni_ < 4; ++ni_)
            acc[mi_][ni_] = __builtin_amdgcn_mfma_f32_16x16x32_bf16(a[mi_], b[ni_], acc[mi_][ni_], 0, 0, 0);
        __builtin_amdgcn_s_setprio(0);
      }
      __builtin_amdgcn_sched_barrier(0);
      __builtin_amdgcn_s_barrier();
    }

    // ---- per-tile epilogue (next tile's kt=0 stage is in flight) ----
    const int colbase = colgroup + nt * 256;
    float csqv[4];
#pragma unroll
    for (int ni = 0; ni < 4; ++ni) csqv[ni] = csq[colbase + wn*64 + ni*16 + l15];

#pragma unroll
    for (int mi = 0; mi < 4; ++mi) {
#pragma unroll
      for (int r = 0; r < 4; ++r) {
        float mn = 1e30f;
#pragma unroll
        for (int ni = 0; ni < 4; ++ni) mn = fminf(mn, fmaf(-2.0f, acc[mi][ni][r], csqv[ni]));
#pragma unroll
        for (int msk = 1; msk < 16; msk <<= 1) mn = fminf(mn, __shfl_xor(mn, msk, 64));
        if (l15 == 0) {
          const int rowl = wm*64 + mi*16 + l4*4 + r;
          atomicMin(&rowthr[rowl], f2key(mn));
        }
      }
    }
    __syncthreads();
    if (t < 128) {
      unsigned int lk = rowthr[t];
      unsigned int old = atomicMin(&rowminG[rowbase + t], lk);
      if (old < lk) atomicMin(&rowthr[t], old);
    }
    __syncthreads();
#pragma unroll
    for (int mi = 0; mi < 4; ++mi) {
#pragma unroll
      for (int r = 0; r < 4; ++r) {
        const int rowl = wm*64 + mi*16 + l4*4 + r;
        const float thr = key2f(rowthr[rowl]) + SCORE_DELTA;
#pragma unroll
        for (int ni = 0; ni < 4; ++ni) {
          float sv = fmaf(-2.0f, acc[mi][ni][r], csqv[ni]);
          if (sv <= thr) {
            const int grow = rowbase + rowl;
            unsigned int old = atomicAdd(&cnt[grow], 1u);
            if (old < CAND_MAX) {
              candI[(size_t)grow * CAND_MAX + old] = colbase + wn*64 + ni*16 + l15;
              candS[(size_t)grow * CAND_MAX + old] = sv;
            }
          }
        }
      }
    }
    __syncthreads();                       // all reads of rowthr done
    if (t < 128) rowthr[t] = 0xFFFFFFFFu;  // reset for next tile (ordered by
                                           // the next tile's KITER barriers)
  }
}

// ------- exact fp32/fp64 rescore, filtered by stored bf16-MFMA scores --------
__global__ __launch_bounds__(256) void k_fixup(const float* __restrict__ x,
    const float* __restrict__ lnw, const float* __restrict__ lnb,
    const float* __restrict__ Gt, const double* __restrict__ csq_d,
    const unsigned int* __restrict__ cnt, const int* __restrict__ candI,
    const float* __restrict__ candS, int* __restrict__ out) {
  __shared__ float xs[4][DDIM];
  const int wave = threadIdx.x >> 6;
  const int lane = threadIdx.x & 63;
  const int row = blockIdx.x * 4 + wave;

  const float4* xr = (const float4*)(x + (size_t)row * DDIM);
  float4 v0 = xr[2*lane], v1 = xr[2*lane+1];
  float s = v0.x + v0.y + v0.z + v0.w + v1.x + v1.y + v1.z + v1.w;
#pragma unroll
  for (int m = 1; m < 64; m <<= 1) s += __shfl_xor(s, m, 64);
  const float mu = s * (1.0f / DDIM);
  float a0 = v0.x - mu, a1 = v0.y - mu, a2 = v0.z - mu, a3 = v0.w - mu;
  float a4 = v1.x - mu, a5 = v1.y - mu, a6 = v1.z - mu, a7 = v1.w - mu;
  float q = a0*a0 + a1*a1 + a2*a2 + a3*a3 + a4*a4 + a5*a5 + a6*a6 + a7*a7;
#pragma unroll
  for (int m = 1; m < 64; m <<= 1) q += __shfl_xor(q, m, 64);
  const float inv = rsqrtf(q * (1.0f / DDIM) + LN_EPS);
  const float4* wr = (const float4*)lnw;
  const float4* br = (const float4*)lnb;
  float4 w0 = wr[2*lane], w1 = wr[2*lane+1];
  float4 b0 = br[2*lane], b1 = br[2*lane+1];
  const float y0 = a0*inv*w0.x + b0.x, y1 = a1*inv*w0.y + b0.y;
  const float y2 = a2*inv*w0.z + b0.z, y3 = a3*inv*w0.w + b0.w;
  const float y4 = a4*inv*w1.x + b1.x, y5 = a5*inv*w1.y + b1.y;
  const float y6 = a6*inv*w1.z + b1.z, y7 = a7*inv*w1.w + b1.w;
  ((float4*)xs[wave])[2*lane]   = make_float4(y0, y1, y2, y3);
  ((float4*)xs[wave])[2*lane+1] = make_float4(y4, y5, y6, y7);

  const unsigned int count = cnt[row];
  double bs = 1e300;
  int bi = 0x7FFFFFFF;
  if (count <= CAND_MAX) {
    // lane i holds candidate i; filter by stored approximate score
    float si = 1e30f;
    int   ci = 0x7FFFFFFF;
    if (lane < (int)count) {
      si = candS[(size_t)row * CAND_MAX + lane];
      ci = candI[(size_t)row * CAND_MAX + lane];
    }
    float bsbf = si;
#pragma unroll
    for (int m = 1; m < 64; m <<= 1) bsbf = fminf(bsbf, __shfl_xor(bsbf, m, 64));
    unsigned long long mask = __ballot(si <= bsbf + RESCORE_WIN);
    while (mask) {
      const int l = __ffsll((long long)mask) - 1;
      mask &= mask - 1;
      const int n = __shfl(ci, l, 64);
      const float4* gr = (const float4*)(Gt + (size_t)n * DDIM);
      float4 g0 = gr[2*lane], g1 = gr[2*lane+1];
      float p = y0*g0.x;
      p = fmaf(y1, g0.y, p); p = fmaf(y2, g0.z, p); p = fmaf(y3, g0.w, p);
      p = fmaf(y4, g1.x, p); p = fmaf(y5, g1.y, p); p = fmaf(y6, g1.z, p);
      p = fmaf(y7, g1.w, p);
#pragma unroll
      for (int m = 1; m < 64; m <<= 1) p += __shfl_xor(p, m, 64);
      double sc = csq_d[n] - 2.0 * (double)p;
      if (sc < bs || (sc == bs && n < bi)) { bs = sc; bi = n; }
    }
    if (lane == 0) out[row] = bi;
  } else {
    // overflow: exact scan of all columns for this row (rare)
    for (int n = lane; n < CDIM; n += 64) {
      const float* g = Gt + (size_t)n * DDIM;
      float p = 0.f;
      for (int d = 0; d < DDIM; ++d) p = fmaf(xs[wave][d], g[d], p);
      double sc = csq_d[n] - 2.0 * (double)p;
      if (sc < bs || (sc == bs && n < bi)) { bs = sc; bi = n; }
    }
#pragma unroll
    for (int m = 1; m < 64; m <<= 1) {
      double os = __shfl_xor(bs, m, 64);
      int oi = __shfl_xor(bi, m, 64);
      if (os < bs || (os == bs && oi < bi)) { bs = os; bi = oi; }
    }
    if (lane == 0) out[row] = bi;
  }
}

extern "C" void kernel_launch(void* const* d_in, const int* in_sizes, int n_in,
                              void* d_out, int out_size, void* d_ws, size_t ws_size,
                              hipStream_t stream) {
  const float* x   = (const float*)d_in[0];
  const float* lnw = (const float*)d_in[1];
  const float* lnb = (const float*)d_in[2];
  const float* W   = (const float*)d_in[3];
  const float* cb  = (const float*)d_in[4];
  int* out = (int*)d_out;

  char* ws = (char*)d_ws;
  size_t off = 0;
  __hip_bfloat16* xb  = (__hip_bfloat16*)(ws + off); off += (size_t)MROWS * DDIM * 2;     // 16MB
  float*          Gt  = (float*)(ws + off);          off += (size_t)CDIM * DDIM * 4;      // 16MB
  __hip_bfloat16* Gtb = (__hip_bfloat16*)(ws + off); off += (size_t)CDIM * DDIM * 2;      // 8MB
  float*          csqf= (float*)(ws + off);          off += (size_t)CDIM * 4;
  double*         csqd= (double*)(ws + off);         off += (size_t)CDIM * 8;
  unsigned int*   cnt = (unsigned int*)(ws + off);   off += (size_t)MROWS * 4;
  unsigned int*   rmin= (unsigned int*)(ws + off);   off += (size_t)MROWS * 4;
  int*            candI=(int*)(ws + off);            off += (size_t)MROWS * CAND_MAX * 4; // 4MB
  float*          candS=(float*)(ws + off);          off += (size_t)MROWS * CAND_MAX * 4; // 4MB

  k_ln<<<MROWS / 4, 256, 0, stream>>>(x, lnw, lnb, xb, cnt, rmin);
  k_csq<<<CDIM / 256, 256, 0, stream>>>(cb, csqf, csqd);
  k_gproj<<<dim3(CDIM / 128, DDIM / 64), dim3(16, 16), 0, stream>>>(W, cb, Gt, Gtb);
  k_score<<<(MROWS / 128) * (CDIM / 2048), 512, 0, stream>>>(xb, Gtb, csqf, rmin, cnt, candI, candS);
  k_fixup<<<MROWS / 4, 256, 0, stream>>>(x, lnw, lnb, Gt, csqd, cnt, candI, candS, out);
}

// Round 10
// 300.838 us; speedup vs baseline: 1.5180x; 1.5180x over previous
//
#include <hip/hip_runtime.h>
#include <hip/hip_bf16.h>

#define MROWS 16384   // B*L
#define DDIM  512
#define HDIM  1024
#define CDIM  8192
#define LN_EPS 1e-5f
#define CAND_MAX 64
#define SCORE_DELTA 3.0f
#define RESCORE_WIN 3.0f

typedef __attribute__((ext_vector_type(8))) short bf16x8;
typedef __attribute__((ext_vector_type(4))) float f32x4;

__device__ __forceinline__ unsigned int f2key(float f) {
  unsigned int b = __float_as_uint(f);
  return (b & 0x80000000u) ? ~b : (b | 0x80000000u);
}
__device__ __forceinline__ float key2f(unsigned int k) {
  unsigned int b = (k & 0x80000000u) ? (k ^ 0x80000000u) : ~k;
  return __uint_as_float(b);
}

// hi/lo bf16 split: x ~= hi + lo, captures ~17 mantissa bits.
__device__ __forceinline__ void bsplit(float v, unsigned short& h, unsigned short& l) {
  union { __hip_bfloat16 b; unsigned short u; } cv;
  cv.b = __float2bfloat16(v);
  h = cv.u;
  float fh = __bfloat162float(cv.b);
  cv.b = __float2bfloat16(v - fh);
  l = cv.u;
}

// -------- LayerNorm -> bf16 (one wave per row, 4 rows/block) + cnt/rmin init --
__global__ __launch_bounds__(256) void k_ln(const float* __restrict__ x,
                                            const float* __restrict__ lnw,
                                            const float* __restrict__ lnb,
                                            __hip_bfloat16* __restrict__ xb,
                                            unsigned int* __restrict__ cnt,
                                            unsigned int* __restrict__ rmin) {
  const int row = blockIdx.x * 4 + (threadIdx.x >> 6);
  const int t = threadIdx.x & 63;
  if (threadIdx.x < 4) {
    const int g = blockIdx.x * 4 + threadIdx.x;
    cnt[g] = 0u;
    rmin[g] = 0xFFFFFFFFu;
  }
  const float4* xr = (const float4*)(x + (size_t)row * DDIM);
  float4 v0 = xr[2 * t + 0];
  float4 v1 = xr[2 * t + 1];
  float s = v0.x + v0.y + v0.z + v0.w + v1.x + v1.y + v1.z + v1.w;
#pragma unroll
  for (int m = 1; m < 64; m <<= 1) s += __shfl_xor(s, m, 64);
  const float mu = s * (1.0f / DDIM);
  float a0 = v0.x - mu, a1 = v0.y - mu, a2 = v0.z - mu, a3 = v0.w - mu;
  float a4 = v1.x - mu, a5 = v1.y - mu, a6 = v1.z - mu, a7 = v1.w - mu;
  float q = a0*a0 + a1*a1 + a2*a2 + a3*a3 + a4*a4 + a5*a5 + a6*a6 + a7*a7;
#pragma unroll
  for (int m = 1; m < 64; m <<= 1) q += __shfl_xor(q, m, 64);
  const float inv = rsqrtf(q * (1.0f / DDIM) + LN_EPS);
  const float4* wr = (const float4*)lnw;
  const float4* br = (const float4*)lnb;
  float4 w0 = wr[2*t+0], w1 = wr[2*t+1];
  float4 b0 = br[2*t+0], b1 = br[2*t+1];
  float y[8];
  y[0] = a0*inv*w0.x + b0.x;  y[1] = a1*inv*w0.y + b0.y;
  y[2] = a2*inv*w0.z + b0.z;  y[3] = a3*inv*w0.w + b0.w;
  y[4] = a4*inv*w1.x + b1.x;  y[5] = a5*inv*w1.y + b1.y;
  y[6] = a6*inv*w1.z + b1.z;  y[7] = a7*inv*w1.w + b1.w;
  union { unsigned short u[8]; uint4 v4; } o;
#pragma unroll
  for (int i = 0; i < 8; ++i) {
    union { __hip_bfloat16 h; unsigned short us; } cv;
    cv.h = __float2bfloat16(y[i]);
    o.u[i] = cv.us;
  }
  *(uint4*)(xb + (size_t)row * DDIM + 8 * t) = o.v4;
}

// ---- W[1024][512] -> WTh/WTl [512][1024] bf16 (transpose + hi/lo split) -----
__global__ __launch_bounds__(256) void k_wsplit(const float* __restrict__ W,
                                                unsigned short* __restrict__ WTh,
                                                unsigned short* __restrict__ WTl) {
  const int c = blockIdx.x * 64 + (threadIdx.x & 63);   // d-column
  const int seg = threadIdx.x >> 6;                     // 4 segs x 256 h
  for (int h0 = seg * 256; h0 < seg * 256 + 256; h0 += 8) {
    union { unsigned short u[8]; uint4 v; } oh, ol;
#pragma unroll
    for (int j = 0; j < 8; ++j) {
      float v = W[(size_t)(h0 + j) * DDIM + c];
      bsplit(v, oh.u[j], ol.u[j]);
    }
    *(uint4*)(WTh + (size_t)c * HDIM + h0) = oh.v;
    *(uint4*)(WTl + (size_t)c * HDIM + h0) = ol.v;
  }
}

// ---- cb[1024][8192] -> cbTh/cbTl [8192][1024] bf16 + csq (fp64, determ.) ----
__global__ __launch_bounds__(256) void k_cbsplit(const float* __restrict__ cb,
                                                 unsigned short* __restrict__ cbTh,
                                                 unsigned short* __restrict__ cbTl,
                                                 float* __restrict__ csq_f,
                                                 double* __restrict__ csq_d) {
  __shared__ double part[4][64];
  const int cl = threadIdx.x & 63;
  const int c = blockIdx.x * 64 + cl;
  const int seg = threadIdx.x >> 6;   // 4 segs x 256 h
  double sq = 0.0;
  for (int h0 = seg * 256; h0 < seg * 256 + 256; h0 += 8) {
    union { unsigned short u[8]; uint4 v; } oh, ol;
#pragma unroll
    for (int j = 0; j < 8; ++j) {
      float v = cb[(size_t)(h0 + j) * CDIM + c];
      sq += (double)v * (double)v;          // fixed order: h ascending in seg
      bsplit(v, oh.u[j], ol.u[j]);
    }
    *(uint4*)(cbTh + (size_t)c * HDIM + h0) = oh.v;
    *(uint4*)(cbTl + (size_t)c * HDIM + h0) = ol.v;
  }
  part[seg][cl] = sq;
  __syncthreads();
  if (threadIdx.x < 64) {
    double a = ((part[0][threadIdx.x] + part[1][threadIdx.x]) +
                part[2][threadIdx.x]) + part[3][threadIdx.x];   // fixed order
    csq_d[c] = a;
    csq_f[c] = (float)a;
  }
}

// ==== Gt[n][d] via bf16x3 MFMA: 64n x 128d tile, K=1024, BK=32, dbuf ==========
// A = cbT hi/lo [8192][1024] bf16, B = WT hi/lo [512][1024] bf16, both [row][k]
// -> identical staging geometry to the verified R6/R8 engine (lane x 16B
// gload_lds, quad-swizzle p = g ^ ((row>>1)&3), sce = (t&3)^((t>>3)&3)).
// acc += ah*bh + ah*bl + al*bh (lo*lo ~ 2^-32, dropped): ~fp32-quality G.
#define GLL(SRC, DST) __builtin_amdgcn_global_load_lds( \
    (const __attribute__((address_space(1))) unsigned int*)(SRC), \
    (__attribute__((address_space(3))) unsigned int*)(DST), 16, 0, 0)

#define GSTAGE(KT) { \
  const int rb_ = ((KT) & 1) * 24576; \
  const int co_ = (KT)*32 + sce*8; \
  GLL(gAh + (size_t)sr0 * HDIM + co_,        lds + rb_ +          t*16); \
  GLL(gAl + (size_t)sr0 * HDIM + co_,        lds + rb_ +  4096 +  t*16); \
  GLL(gBh + (size_t)sr0 * HDIM + co_,        lds + rb_ +  8192 +  t*16); \
  GLL(gBh + (size_t)(sr0 + 64) * HDIM + co_, lds + rb_ + 12288 +  t*16); \
  GLL(gBl + (size_t)sr0 * HDIM + co_,        lds + rb_ + 16384 +  t*16); \
  GLL(gBl + (size_t)(sr0 + 64) * HDIM + co_, lds + rb_ + 20480 +  t*16); }

__global__ __launch_bounds__(256) void k_gproj2(
    const unsigned short* __restrict__ cbTh, const unsigned short* __restrict__ cbTl,
    const unsigned short* __restrict__ WTh,  const unsigned short* __restrict__ WTl,
    float* __restrict__ Gt, __hip_bfloat16* __restrict__ Gtb) {
  __shared__ __align__(16) char lds[49152];
  const int t = threadIdx.x;
  const int wave = t >> 6;
  const int lane = t & 63;
  const int l15 = lane & 15;
  const int l4  = lane >> 4;
  const int wm = wave >> 1;   // 2 waves in M (32 n-rows each)
  const int wn = wave & 1;    // 2 waves in N (64 d-cols each)

  const int bid = blockIdx.x;                    // 512 blocks
  const int sbid = (bid & 7) * 64 + (bid >> 3);  // XCD-chunked (512 % 8 == 0)
  const int d_blk = sbid >> 7;                   // 0..3
  const int m_blk = sbid & 127;                  // 0..127
  const int rowbase = m_blk * 64;                // n
  const int colbase = d_blk * 128;               // d

  const unsigned short* gAh = cbTh + (size_t)rowbase * HDIM;
  const unsigned short* gAl = cbTl + (size_t)rowbase * HDIM;
  const unsigned short* gBh = WTh + (size_t)colbase * HDIM;
  const unsigned short* gBl = WTl + (size_t)colbase * HDIM;

  const int sr0 = t >> 2;                     // 0..63
  const int sce = (t & 3) ^ ((t >> 3) & 3);   // inverse-swizzled source slot

  const int swz = ((l4 ^ ((l15 >> 1) & 3)) << 4);
  const int aoffb = (wm * 32 + l15) * 64 + swz;
  const int boffb = (wn * 64 + l15) * 64 + swz;

  f32x4 acc[2][4];
#pragma unroll
  for (int i = 0; i < 2; ++i)
#pragma unroll
    for (int j = 0; j < 4; ++j) acc[i][j] = (f32x4){0.f, 0.f, 0.f, 0.f};

  GSTAGE(0);
#pragma unroll 4
  for (int kt = 0; kt < 32; ++kt) {
    if (kt < 31) {
      GSTAGE(kt + 1);
      asm volatile("s_waitcnt vmcnt(6)" ::: "memory");
    } else {
      asm volatile("s_waitcnt vmcnt(0)" ::: "memory");
    }
    __builtin_amdgcn_s_barrier();
    __builtin_amdgcn_sched_barrier(0);
    {
      const char* Sb_ = lds + (kt & 1) * 24576;
      bf16x8 ah[2], al[2], bh[4], bl[4];
#pragma unroll
      for (int ni = 0; ni < 4; ++ni) {
        bh[ni] = *(const bf16x8*)(Sb_ +  8192 + boffb + ni * 1024);
        bl[ni] = *(const bf16x8*)(Sb_ + 16384 + boffb + ni * 1024);
      }
#pragma unroll
      for (int mi = 0; mi < 2; ++mi) {
        ah[mi] = *(const bf16x8*)(Sb_ +        aoffb + mi * 1024);
        al[mi] = *(const bf16x8*)(Sb_ + 4096 + aoffb + mi * 1024);
      }
      __builtin_amdgcn_s_setprio(1);
#pragma unroll
      for (int mi = 0; mi < 2; ++mi)
#pragma unroll
        for (int ni = 0; ni < 4; ++ni) {
          acc[mi][ni] = __builtin_amdgcn_mfma_f32_16x16x32_bf16(ah[mi], bh[ni], acc[mi][ni], 0, 0, 0);
          acc[mi][ni] = __builtin_amdgcn_mfma_f32_16x16x32_bf16(ah[mi], bl[ni], acc[mi][ni], 0, 0, 0);
          acc[mi][ni] = __builtin_amdgcn_mfma_f32_16x16x32_bf16(al[mi], bh[ni], acc[mi][ni], 0, 0, 0);
        }
      __builtin_amdgcn_s_setprio(0);
    }
    __builtin_amdgcn_sched_barrier(0);
    __builtin_amdgcn_s_barrier();
  }

  // epilogue: C[n][d] -> Gt fp32 + Gtb bf16 (16 lanes = 16 consecutive d)
#pragma unroll
  for (int mi = 0; mi < 2; ++mi) {
#pragma unroll
    for (int r = 0; r < 4; ++r) {
      const int n = rowbase + wm*32 + mi*16 + l4*4 + r;
#pragma unroll
      for (int ni = 0; ni < 4; ++ni) {
        const int d = colbase + wn*64 + ni*16 + l15;
        const float v = acc[mi][ni][r];
        Gt[(size_t)n * DDIM + d] = v;
        union { __hip_bfloat16 h; unsigned short us; } cv;
        cv.h = __float2bfloat16(v);
        *((unsigned short*)Gtb + (size_t)n * DDIM + d) = cv.us;
      }
    }
  }
}

// ====== 128x256 MFMA scoring: BK=32, double-buffer, 2 blocks/CU (R6 exact) ====
#define STAGE24(KT) { \
  const int rb_ = ((KT) & 1) * 24576; \
  GLL(gA + (size_t)sr0 * 512 + ((KT)*32 + sce*8), lds + rb_ +         t*16); \
  GLL(gB + (size_t)sr0 * 512 + ((KT)*32 + sce*8), lds + rb_ +  8192 + t*16); \
  GLL(gB + (size_t)(sr0 + 128) * 512 + ((KT)*32 + sce*8), lds + rb_ + 16384 + t*16); }

#define KITER(T, DOSTAGE, WAITSTR) do { \
  if (DOSTAGE) STAGE24((T) + 1); \
  asm volatile("s_waitcnt " WAITSTR ::: "memory"); \
  __builtin_amdgcn_s_barrier(); \
  __builtin_amdgcn_sched_barrier(0); \
  { \
    const char* Sb_ = lds + ((T) & 1) * 24576; \
    bf16x8 a[4], b[4]; \
    _Pragma("unroll") for (int ni_ = 0; ni_ < 4; ++ni_) \
      b[ni_] = *(const bf16x8*)(Sb_ + 8192 + boffb + ni_ * 1024); \
    _Pragma("unroll") for (int mi_ = 0; mi_ < 4; ++mi_) \
      a[mi_] = *(const bf16x8*)(Sb_ + aoffb + mi_ * 1024); \
    __builtin_amdgcn_s_setprio(1); \
    _Pragma("unroll") for (int mi_ = 0; mi_ < 4; ++mi_) \
    _Pragma("unroll") for (int ni_ = 0; ni_ < 4; ++ni_) \
      acc[mi_][ni_] = __builtin_amdgcn_mfma_f32_16x16x32_bf16(a[mi_], b[ni_], acc[mi_][ni_], 0, 0, 0); \
    __builtin_amdgcn_s_setprio(0); \
  } \
  __builtin_amdgcn_sched_barrier(0); \
  __builtin_amdgcn_s_barrier(); \
} while (0)

__global__ __launch_bounds__(512, 4) void k_score(
    const __hip_bfloat16* __restrict__ xb,   // [16384][512]
    const __hip_bfloat16* __restrict__ Gtb,  // [8192][512]
    const float* __restrict__ csq,           // [8192]
    unsigned int* __restrict__ rowminG,      // [16384] key-encoded, init 0xFF
    unsigned int* __restrict__ cnt,          // [16384]
    int* __restrict__ candI,                 // [16384][CAND_MAX]
    float* __restrict__ candS)               // [16384][CAND_MAX]
{
  __shared__ __align__(16) char lds[49152];
  __shared__ unsigned int rowthr[128];

  const int t = threadIdx.x;
  const int wave = t >> 6;
  const int lane = t & 63;
  const int l15 = lane & 15;
  const int l4  = lane >> 4;
  const int wm = wave >> 2;   // 2 waves in M (64 rows each)
  const int wn = wave & 3;    // 4 waves in N (64 cols each)

  const int bid = blockIdx.x;
  const int sbid = (bid & 7) * 512 + (bid >> 3);
  const int n_blk = sbid >> 7;   // 0..31
  const int m_blk = sbid & 127;  // 0..127
  const int rowbase = m_blk * 128;
  const int colbase = n_blk * 256;

  const unsigned short* gA = (const unsigned short*)xb  + (size_t)rowbase * 512;
  const unsigned short* gB = (const unsigned short*)Gtb + (size_t)colbase * 512;

  const int sr0 = t >> 2;                     // 0..127
  const int sce = (t & 3) ^ ((t >> 3) & 3);   // inverse-swizzled global slot

  if (t < 128) rowthr[t] = 0xFFFFFFFFu;

  const int swz = ((l4 ^ ((l15 >> 1) & 3)) << 4);
  const int aoffb = (wm * 64 + l15) * 64 + swz;
  const int boffb = (wn * 64 + l15) * 64 + swz;

  f32x4 acc[4][4];
#pragma unroll
  for (int i = 0; i < 4; ++i)
#pragma unroll
    for (int j = 0; j < 4; ++j) acc[i][j] = (f32x4){0.f, 0.f, 0.f, 0.f};

  STAGE24(0);
  KITER( 0, 1, "vmcnt(3)");
  KITER( 1, 1, "vmcnt(3)");
  KITER( 2, 1, "vmcnt(3)");
  KITER( 3, 1, "vmcnt(3)");
  KITER( 4, 1, "vmcnt(3)");
  KITER( 5, 1, "vmcnt(3)");
  KITER( 6, 1, "vmcnt(3)");
  KITER( 7, 1, "vmcnt(3)");
  KITER( 8, 1, "vmcnt(3)");
  KITER( 9, 1, "vmcnt(3)");
  KITER(10, 1, "vmcnt(3)");
  KITER(11, 1, "vmcnt(3)");
  KITER(12, 1, "vmcnt(3)");
  KITER(13, 1, "vmcnt(3)");
  KITER(14, 1, "vmcnt(3)");
  KITER(15, 0, "vmcnt(0)");

  float csqv[4];
#pragma unroll
  for (int ni = 0; ni < 4; ++ni) csqv[ni] = csq[colbase + wn*64 + ni*16 + l15];

#pragma unroll
  for (int mi = 0; mi < 4; ++mi) {
#pragma unroll
    for (int r = 0; r < 4; ++r) {
      float mn = 1e30f;
#pragma unroll
      for (int ni = 0; ni < 4; ++ni) mn = fminf(mn, fmaf(-2.0f, acc[mi][ni][r], csqv[ni]));
#pragma unroll
      for (int msk = 1; msk < 16; msk <<= 1) mn = fminf(mn, __shfl_xor(mn, msk, 64));
      if (l15 == 0) {
        const int rowl = wm*64 + mi*16 + l4*4 + r;
        atomicMin(&rowthr[rowl], f2key(mn));
      }
    }
  }
  __syncthreads();
  if (t < 128) {
    unsigned int lk = rowthr[t];
    unsigned int old = atomicMin(&rowminG[rowbase + t], lk);
    if (old < lk) atomicMin(&rowthr[t], old);
  }
  __syncthreads();
#pragma unroll
  for (int mi = 0; mi < 4; ++mi) {
#pragma unroll
    for (int r = 0; r < 4; ++r) {
      const int rowl = wm*64 + mi*16 + l4*4 + r;
      const float thr = key2f(rowthr[rowl]) + SCORE_DELTA;
#pragma unroll
      for (int ni = 0; ni < 4; ++ni) {
        float sv = fmaf(-2.0f, acc[mi][ni][r], csqv[ni]);
        if (sv <= thr) {
          const int grow = rowbase + rowl;
          unsigned int old = atomicAdd(&cnt[grow], 1u);
          if (old < CAND_MAX) {
            candI[(size_t)grow * CAND_MAX + old] = colbase + wn*64 + ni*16 + l15;
            candS[(size_t)grow * CAND_MAX + old] = sv;
          }
        }
      }
    }
  }
}

// ------- exact fp32/fp64 rescore, filtered by stored bf16-MFMA scores --------
__global__ __launch_bounds__(256) void k_fixup(const float* __restrict__ x,
    const float* __restrict__ lnw, const float* __restrict__ lnb,
    const float* __restrict__ Gt, const double* __restrict__ csq_d,
    const unsigned int* __restrict__ cnt, const int* __restrict__ candI,
    const float* __restrict__ candS, int* __restrict__ out) {
  __shared__ float xs[4][DDIM];
  const int wave = threadIdx.x >> 6;
  const int lane = threadIdx.x & 63;
  const int row = blockIdx.x * 4 + wave;

  const float4* xr = (const float4*)(x + (size_t)row * DDIM);
  float4 v0 = xr[2*lane], v1 = xr[2*lane+1];
  float s = v0.x + v0.y + v0.z + v0.w + v1.x + v1.y + v1.z + v1.w;
#pragma unroll
  for (int m = 1; m < 64; m <<= 1) s += __shfl_xor(s, m, 64);
  const float mu = s * (1.0f / DDIM);
  float a0 = v0.x - mu, a1 = v0.y - mu, a2 = v0.z - mu, a3 = v0.w - mu;
  float a4 = v1.x - mu, a5 = v1.y - mu, a6 = v1.z - mu, a7 = v1.w - mu;
  float q = a0*a0 + a1*a1 + a2*a2 + a3*a3 + a4*a4 + a5*a5 + a6*a6 + a7*a7;
#pragma unroll
  for (int m = 1; m < 64; m <<= 1) q += __shfl_xor(q, m, 64);
  const float inv = rsqrtf(q * (1.0f / DDIM) + LN_EPS);
  const float4* wr = (const float4*)lnw;
  const float4* br = (const float4*)lnb;
  float4 w0 = wr[2*lane], w1 = wr[2*lane+1];
  float4 b0 = br[2*lane], b1 = br[2*lane+1];
  const float y0 = a0*inv*w0.x + b0.x, y1 = a1*inv*w0.y + b0.y;
  const float y2 = a2*inv*w0.z + b0.z, y3 = a3*inv*w0.w + b0.w;
  const float y4 = a4*inv*w1.x + b1.x, y5 = a5*inv*w1.y + b1.y;
  const float y6 = a6*inv*w1.z + b1.z, y7 = a7*inv*w1.w + b1.w;
  ((float4*)xs[wave])[2*lane]   = make_float4(y0, y1, y2, y3);
  ((float4*)xs[wave])[2*lane+1] = make_float4(y4, y5, y6, y7);

  const unsigned int count = cnt[row];
  double bs = 1e300;
  int bi = 0x7FFFFFFF;
  if (count <= CAND_MAX) {
    float si = 1e30f;
    int   ci = 0x7FFFFFFF;
    if (lane < (int)count) {
      si = candS[(size_t)row * CAND_MAX + lane];
      ci = candI[(size_t)row * CAND_MAX + lane];
    }
    float bsbf = si;
#pragma unroll
    for (int m = 1; m < 64; m <<= 1) bsbf = fminf(bsbf, __shfl_xor(bsbf, m, 64));
    unsigned long long mask = __ballot(si <= bsbf + RESCORE_WIN);
    while (mask) {
      const int l = __ffsll((long long)mask) - 1;
      mask &= mask - 1;
      const int n = __shfl(ci, l, 64);
      const float4* gr = (const float4*)(Gt + (size_t)n * DDIM);
      float4 g0 = gr[2*lane], g1 = gr[2*lane+1];
      float p = y0*g0.x;
      p = fmaf(y1, g0.y, p); p = fmaf(y2, g0.z, p); p = fmaf(y3, g0.w, p);
      p = fmaf(y4, g1.x, p); p = fmaf(y5, g1.y, p); p = fmaf(y6, g1.z, p);
      p = fmaf(y7, g1.w, p);
#pragma unroll
      for (int m = 1; m < 64; m <<= 1) p += __shfl_xor(p, m, 64);
      double sc = csq_d[n] - 2.0 * (double)p;
      if (sc < bs || (sc == bs && n < bi)) { bs = sc; bi = n; }
    }
    if (lane == 0) out[row] = bi;
  } else {
    for (int n = lane; n < CDIM; n += 64) {
      const float* g = Gt + (size_t)n * DDIM;
      float p = 0.f;
      for (int d = 0; d < DDIM; ++d) p = fmaf(xs[wave][d], g[d], p);
      double sc = csq_d[n] - 2.0 * (double)p;
      if (sc < bs || (sc == bs && n < bi)) { bs = sc; bi = n; }
    }
#pragma unroll
    for (int m = 1; m < 64; m <<= 1) {
      double os = __shfl_xor(bs, m, 64);
      int oi = __shfl_xor(bi, m, 64);
      if (os < bs || (os == bs && oi < bi)) { bs = os; bi = oi; }
    }
    if (lane == 0) out[row] = bi;
  }
}

extern "C" void kernel_launch(void* const* d_in, const int* in_sizes, int n_in,
                              void* d_out, int out_size, void* d_ws, size_t ws_size,
                              hipStream_t stream) {
  const float* x   = (const float*)d_in[0];
  const float* lnw = (const float*)d_in[1];
  const float* lnb = (const float*)d_in[2];
  const float* W   = (const float*)d_in[3];
  const float* cb  = (const float*)d_in[4];
  int* out = (int*)d_out;

  char* ws = (char*)d_ws;
  size_t off = 0;
  __hip_bfloat16* xb  = (__hip_bfloat16*)(ws + off); off += (size_t)MROWS * DDIM * 2;     // 16MB
  float*          Gt  = (float*)(ws + off);          off += (size_t)CDIM * DDIM * 4;      // 16MB
  __hip_bfloat16* Gtb = (__hip_bfloat16*)(ws + off); off += (size_t)CDIM * DDIM * 2;      // 8MB
  unsigned short* cbTh= (unsigned short*)(ws + off); off += (size_t)CDIM * HDIM * 2;      // 16MB
  unsigned short* cbTl= (unsigned short*)(ws + off); off += (size_t)CDIM * HDIM * 2;      // 16MB
  unsigned short* WTh = (unsigned short*)(ws + off); off += (size_t)DDIM * HDIM * 2;      // 2MB
  unsigned short* WTl = (unsigned short*)(ws + off); off += (size_t)DDIM * HDIM * 2;      // 2MB
  float*          csqf= (float*)(ws + off);          off += (size_t)CDIM * 4;
  double*         csqd= (double*)(ws + off);         off += (size_t)CDIM * 8;
  unsigned int*   cnt = (unsigned int*)(ws + off);   off += (size_t)MROWS * 4;
  unsigned int*   rmin= (unsigned int*)(ws + off);   off += (size_t)MROWS * 4;
  int*            candI=(int*)(ws + off);            off += (size_t)MROWS * CAND_MAX * 4; // 4MB
  float*          candS=(float*)(ws + off);          off += (size_t)MROWS * CAND_MAX * 4; // 4MB

  k_ln<<<MROWS / 4, 256, 0, stream>>>(x, lnw, lnb, xb, cnt, rmin);
  k_wsplit<<<DDIM / 64, 256, 0, stream>>>(W, WTh, WTl);
  k_cbsplit<<<CDIM / 64, 256, 0, stream>>>(cb, cbTh, cbTl, csqf, csqd);
  k_gproj2<<<(CDIM / 64) * (DDIM / 128), 256, 0, stream>>>(cbTh, cbTl, WTh, WTl, Gt, Gtb);
  k_score<<<(MROWS / 128) * (CDIM / 256), 512, 0, stream>>>(xb, Gtb, csqf, rmin, cnt, candI, candS);
  k_fixup<<<MROWS / 4, 256, 0, stream>>>(x, lnw, lnb, Gt, csqd, cnt, candI, candS, out);
}